// Round 13
// baseline (159.237 us; speedup 1.0000x reference)
//
#include <hip/hip_runtime.h>

typedef __attribute__((ext_vector_type(8))) _Float16 f16x8;
typedef __attribute__((ext_vector_type(4))) float f32x4;

static constexpr int TT = 100, BB = 256, DD = 784, HH = 256;
static constexpr int MM = TT * BB;      // 25600
static constexpr int K1PAD = 800;       // 784 -> 25*32
static constexpr int N2PAD = 800;       // 784 -> 25*32 (W2 row pad)
static constexpr float MIDSC = 2048.0f, INVMID = 1.0f / 2048.0f;

__device__ __forceinline__ unsigned short f2h(float x) {
  _Float16 h = (_Float16)x;
  return *(unsigned short*)&h;
}
__device__ __forceinline__ float h2f(unsigned short u) {
  _Float16 h = *(_Float16*)&u;
  return (float)h;
}
__device__ __forceinline__ void glds16(const void* g, void* l) {
  __builtin_amdgcn_global_load_lds(
      (const __attribute__((address_space(1))) unsigned int*)g,
      (__attribute__((address_space(3))) unsigned int*)l, 16, 0, 0);
}

// Split fp32 W[N][K] into 2 f16 planes [Npad][Kpad]:
//   p0 = f16(w), p1 = f16((w - p0) * 2048); reconstruct p0 + p1/2048 (~2^-22 rel).
__global__ __launch_bounds__(256)
void split_w(const float* __restrict__ W, unsigned short* __restrict__ Ws,
             int N, int K, int Npad, int Kpad) {
  int idx = blockIdx.x * 256 + threadIdx.x;
  int total = Npad * Kpad;
  if (idx >= total) return;
  int row = idx / Kpad, col = idx - row * Kpad;
  float w = (row < N && col < K) ? W[row * K + col] : 0.0f;
  unsigned short h0 = f2h(w);
  float r = (w - h2f(h0)) * MIDSC;
  Ws[idx] = h0;
  Ws[total + idx] = f2h(r);
}

// Layer-1 GEMM v2: cur1[M,256] = X[M,784](binary fp32) @ (2-plane f16 W1)^T + b1.
// BM=128, BN=256 (FULL N -> X converted once), BK=32, 512 threads = 8 waves
// (2m x 4n), wave tile 64x64, 32 MFMA/step/wave. B: glds 3-buf, A: reg-staged
// binary->f16 (bit trick: f16 = (u32>>16)&0x3C00), ds_written 1 step ahead.
// FIFO discipline: loadA at step TOP (A oldest in queue) so the compiler's
// packA register-wait drains ONLY A; explicit vmcnt(6) leaves B(kb+1)+A(kb+2)
// in flight. XOR-swizzled LDS identical to prior rounds (measured 0 conflicts).
__global__ __launch_bounds__(512, 2)
void gemm1(const float* __restrict__ X, const unsigned short* __restrict__ Bs,
           const float* __restrict__ bias, float* __restrict__ C) {
  constexpr int Kpad = K1PAD, nkb = Kpad / 32;   // 25
  __shared__ unsigned short Asm[2][128 * 32];      // 16 KB
  __shared__ unsigned short Bsm[3][2][256 * 32];   // 96 KB
  const int tid = threadIdx.x;
  const int bm = blockIdx.x * 128;
  const int wid = tid >> 6, lane = tid & 63;
  const int wr = (wid >> 2) * 64, wc = (wid & 3) * 64;
  const int l15 = lane & 15, l4 = lane >> 4;

  f32x4 acc[2][4][4];
#pragma unroll
  for (int s = 0; s < 2; ++s)
#pragma unroll
    for (int m = 0; m < 4; ++m)
#pragma unroll
      for (int n = 0; n < 4; ++n) acc[s][m][n] = (f32x4){0.f, 0.f, 0.f, 0.f};

  // B glds geometry: wave wid stages B rows [wid*32, wid*32+32), 2 instr/plane.
  const int rl = wid * 32 + (lane >> 2);
  const int ce = ((lane & 3) ^ ((lane >> 3) & 3)) * 8;
  const size_t pstr = (size_t)HH * Kpad;
  const unsigned short* bsrc0 = Bs + (size_t)rl * Kpad + ce;
  const unsigned short* bsrc1 = Bs + (size_t)(rl + 16) * Kpad + ce;

  const int rdsw = (l4 ^ ((l15 >> 1) & 3)) * 8;

  // A staging: 512 threads -> 128 rows x 4 col-octets (1 uint4 each)
  const int r0 = tid >> 2;
  const int c0log = (tid & 3) * 8;
  const int c0phys = ((tid & 3) ^ ((tid >> 3) & 3)) * 8;

  float4 aA[2], aB[2];

  auto loadA = [&](int kb, float4 (&d)[2]) {
    const int col = kb * 32 + c0log;
    if (col < DD) {          // 784 % 8 == 0: whole octet in/out
      const float* p = &X[(size_t)(bm + r0) * DD + col];
      d[0] = *(const float4*)p;
      d[1] = *(const float4*)(p + 4);
    } else {
      d[0] = make_float4(0.f, 0.f, 0.f, 0.f);
      d[1] = d[0];
    }
  };
  auto packA = [&](int bi, const float4 (&s_)[2]) {
    // binary fp32 -> f16 pair: ((lo>>16)&0x3C00) | (hi & 0x3C000000)
    auto pk = [](float a, float b) {
      return ((__float_as_uint(a) >> 16) & 0x3C00u) |
             (__float_as_uint(b) & 0x3C000000u);
    };
    uint4 v;
    v.x = pk(s_[0].x, s_[0].y); v.y = pk(s_[0].z, s_[0].w);
    v.z = pk(s_[1].x, s_[1].y); v.w = pk(s_[1].z, s_[1].w);
    *(uint4*)&Asm[bi][r0 * 32 + c0phys] = v;
  };
  auto stageB = [&](int t) {
    const int k0 = t * 32, bi = t % 3;
    glds16(bsrc0 + k0,        &Bsm[bi][0][(wid * 32) * 32]);
    glds16(bsrc1 + k0,        &Bsm[bi][0][(wid * 32 + 16) * 32]);
    glds16(bsrc0 + pstr + k0, &Bsm[bi][1][(wid * 32) * 32]);
    glds16(bsrc1 + pstr + k0, &Bsm[bi][1][(wid * 32 + 16) * 32]);
  };
  auto compute = [&](int kb) {
    const int cb = kb & 1, b3 = kb % 3;
    f16x8 afr[4];
#pragma unroll
    for (int m = 0; m < 4; ++m)
      afr[m] = *(const f16x8*)&Asm[cb][(wr + m * 16 + l15) * 32 + rdsw];
#pragma unroll
    for (int s = 0; s < 2; ++s) {
      f16x8 bfr[4];
#pragma unroll
      for (int n = 0; n < 4; ++n)
        bfr[n] = *(const f16x8*)&Bsm[b3][s][(wc + n * 16 + l15) * 32 + rdsw];
#pragma unroll
      for (int m = 0; m < 4; ++m)
#pragma unroll
        for (int n = 0; n < 4; ++n)
          acc[s][m][n] = __builtin_amdgcn_mfma_f32_16x16x32_f16(afr[m], bfr[n], acc[s][m][n], 0, 0, 0);
    }
  };
  auto stepK = [&](int kb, const float4 (&pk_)[2], float4 (&ld_)[2]) {
    if (kb + 2 < nkb) loadA(kb + 2, ld_);         // A FIRST -> oldest in FIFO
    if (kb + 1 < nkb) packA((kb + 1) & 1, pk_);   // compiler drains only A(kb+1)
    if (kb + 2 < nkb) stageB(kb + 2);
    compute(kb);
    __builtin_amdgcn_sched_barrier(0);
    // FIFO here: [B(kb+1):4, A(kb+2):2, B(kb+2):4] -> vmcnt(6) drains B(kb+1)
    if (kb + 2 < nkb) asm volatile("s_waitcnt vmcnt(6)" ::: "memory");
    else              asm volatile("s_waitcnt vmcnt(0)" ::: "memory");
    asm volatile("s_waitcnt lgkmcnt(0)" ::: "memory");
    __builtin_amdgcn_sched_barrier(0);
    __builtin_amdgcn_s_barrier();
    __builtin_amdgcn_sched_barrier(0);
  };

  // prologue: A0, B0, A1, B1 issued (A oldest); pack A0; drain B0 only.
  loadA(0, aA);
  stageB(0);
  loadA(1, aB);
  stageB(1);
  packA(0, aA);                                   // compiler waits A0 (vmcnt 10)
  asm volatile("s_waitcnt vmcnt(6)" ::: "memory"); // [A1:2,B1:4] left; B0 done
  asm volatile("s_waitcnt lgkmcnt(0)" ::: "memory");
  __builtin_amdgcn_s_barrier();
  __builtin_amdgcn_sched_barrier(0);

  for (int kb2 = 0; kb2 < nkb; kb2 += 2) {
    stepK(kb2, aB, aA);                // pack A(odd) from aB, load A(even+2)->aA
    if (kb2 + 1 < nkb) stepK(kb2 + 1, aA, aB);
  }

#pragma unroll
  for (int m = 0; m < 4; ++m)
#pragma unroll
    for (int n = 0; n < 4; ++n) {
      const int col = wc + n * 16 + l15;
      const float bv = bias[col];
#pragma unroll
      for (int r = 0; r < 4; ++r) {
        const int row = bm + wr + m * 16 + l4 * 4 + r;
        C[(size_t)row * HH + col] = fmaf(acc[1][m][n][r], INVMID, acc[0][m][n][r]) + bv;
      }
    }
}

// fp32 currents -> f16 spikes, 4 elems/thread
__global__ __launch_bounds__(256)
void lif_scan_h4(const float4* __restrict__ cur, uint2* __restrict__ spk,
                 int NE4, int nt) {
  const int tid = blockIdx.x * 256 + threadIdx.x;
  float4 mem = make_float4(0.f, 0.f, 0.f, 0.f);
  auto step1 = [](float& m, float c) {
    const float reset = (m > 1.0f) ? 1.0f : 0.0f;
    m = __fsub_rn(__fadd_rn(__fmul_rn(0.9f, m), c), reset);
    return (m > 1.0f);
  };
#pragma unroll 4
  for (int t = 0; t < nt; ++t) {
    const float4 c = cur[(size_t)t * NE4 + tid];
    unsigned s0 = step1(mem.x, c.x) ? 0x3C00u : 0u;
    unsigned s1 = step1(mem.y, c.y) ? 0x3C00u : 0u;
    unsigned s2 = step1(mem.z, c.z) ? 0x3C00u : 0u;
    unsigned s3 = step1(mem.w, c.w) ? 0x3C00u : 0u;
    uint2 o;
    o.x = s0 | (s1 << 16);
    o.y = s2 | (s3 << 16);
    spk[(size_t)t * NE4 + tid] = o;
  }
}

// Fused layer-2 GEMM + LIF v7: ONE WAVE per block owns TWO d-tiles (16b x 32d)
// sharing the SAME A-slice: LDS reads/t stay 8 while MFMAs double to 32.
// Zero barriers; counted vmcnt (stores never drained mid-loop). Per-tile MFMA
// chains + LIF ops identical to r12 -> layer-2 output bitwise identical.
// FIFO at iter-t wait (after stage(t+2)): items after stage(t) =
//   stores(t-2):S + stage(t+1):8 + stores(t-1):S + stage(t+2):8, S = st2?8:4
//   -> vmcnt(32|24). t<2: 16. t=98: 24|16. t=99: 16|8.
__global__ __launch_bounds__(64)
void fused_l2(const unsigned short* __restrict__ spk1,   // [100][256][256] f16
              const unsigned short* __restrict__ W2s,    // 2 planes [800][256] f16
              const float* __restrict__ b2, float* __restrict__ out) {
  __shared__ unsigned short Asm[4][16 * 256];   // 32 KB ring
  const int lane = threadIdx.x;                  // 64
  const int l15 = lane & 15, l4 = lane >> 4;
  const int bb = blockIdx.x / 25, pr = blockIdx.x - bb * 25;  // 16 x 25
  const int b0 = bb * 16, d0 = pr * 32;
  const bool st2 = (d0 + 16) < DD;               // only pr==24 false

  // W2 fragments: 2 tiles x 2 planes x 8 k-chunks = 128 VGPR
  f16x8 w1[2][8], w2[2][8];
  const unsigned short* wb1 = W2s + (size_t)(d0 + l15) * HH + l4 * 8;
  const unsigned short* wb2 = W2s + (size_t)(d0 + 16 + l15) * HH + l4 * 8;
#pragma unroll
  for (int s = 0; s < 2; ++s)
#pragma unroll
    for (int ks = 0; ks < 8; ++ks) {
      w1[s][ks] = *(const f16x8*)(wb1 + (size_t)s * (N2PAD * HH) + ks * 32);
      w2[s][ks] = *(const f16x8*)(wb2 + (size_t)s * (N2PAD * HH) + ks * 32);
    }
  const float bv1 = b2[d0 + l15];
  const float bv2 = st2 ? b2[d0 + 16 + l15] : 0.f;

  // glds: instr i covers rows 2i,2i+1; source col pre-swizzled by ^((r&7)<<3).
  const unsigned short* asrc[8];
#pragma unroll
  for (int i = 0; i < 8; ++i) {
    const int r = 2 * i + (lane >> 5);
    const int e = ((lane & 31) * 8) ^ ((r & 7) << 3);
    asrc[i] = spk1 + (size_t)(b0 + r) * HH + e;
  }
  auto stageA = [&](int t) {
    const size_t toff = (size_t)t * (BB * HH);
    unsigned short* dst = &Asm[t & 3][0];
#pragma unroll
    for (int i = 0; i < 8; ++i)
      glds16(asrc[i] + toff, dst + 2 * i * 256);
  };

  stageA(0);
  stageA(1);

  f32x4 mem1 = (f32x4){0.f, 0.f, 0.f, 0.f}, mem2 = mem1;
  float* ob1 = out + (size_t)(b0 + l4 * 4) * DD + d0 + l15;
  float* ob2 = ob1 + 16;

  for (int t = 0; t < TT; ++t) {
    if (t + 2 < TT) stageA(t + 2);
    // counted wait (wave-uniform): drain stage(t), keep later stages + stores
    if (t < 2) {
      asm volatile("s_waitcnt vmcnt(16)" ::: "memory");
    } else if (t <= 97) {
      if (st2) asm volatile("s_waitcnt vmcnt(32)" ::: "memory");
      else     asm volatile("s_waitcnt vmcnt(24)" ::: "memory");
    } else if (t == 98) {
      if (st2) asm volatile("s_waitcnt vmcnt(24)" ::: "memory");
      else     asm volatile("s_waitcnt vmcnt(16)" ::: "memory");
    } else {
      if (st2) asm volatile("s_waitcnt vmcnt(16)" ::: "memory");
      else     asm volatile("s_waitcnt vmcnt(8)" ::: "memory");
    }
    __builtin_amdgcn_sched_barrier(0);

    const unsigned short* abuf = &Asm[t & 3][0];
    f32x4 q0a = (f32x4){0.f, 0.f, 0.f, 0.f}, q0b = q0a, q1a = q0a, q1b = q0a;
    f32x4 u0a = q0a, u0b = q0a, u1a = q0a, u1b = q0a;
#pragma unroll
    for (int ks = 0; ks < 4; ++ks) {
      const f16x8 a = *(const f16x8*)&abuf[l15 * 256 + ((ks * 32 + l4 * 8) ^ ((l15 & 7) << 3))];
      q0a = __builtin_amdgcn_mfma_f32_16x16x32_f16(a, w1[0][ks], q0a, 0, 0, 0);
      q1a = __builtin_amdgcn_mfma_f32_16x16x32_f16(a, w1[1][ks], q1a, 0, 0, 0);
      u0a = __builtin_amdgcn_mfma_f32_16x16x32_f16(a, w2[0][ks], u0a, 0, 0, 0);
      u1a = __builtin_amdgcn_mfma_f32_16x16x32_f16(a, w2[1][ks], u1a, 0, 0, 0);
    }
#pragma unroll
    for (int ks = 4; ks < 8; ++ks) {
      const f16x8 a = *(const f16x8*)&abuf[l15 * 256 + ((ks * 32 + l4 * 8) ^ ((l15 & 7) << 3))];
      q0b = __builtin_amdgcn_mfma_f32_16x16x32_f16(a, w1[0][ks], q0b, 0, 0, 0);
      q1b = __builtin_amdgcn_mfma_f32_16x16x32_f16(a, w1[1][ks], q1b, 0, 0, 0);
      u0b = __builtin_amdgcn_mfma_f32_16x16x32_f16(a, w2[0][ks], u0b, 0, 0, 0);
      u1b = __builtin_amdgcn_mfma_f32_16x16x32_f16(a, w2[1][ks], u1b, 0, 0, 0);
    }

    const size_t to = (size_t)t * ((size_t)BB * DD);
#pragma unroll
    for (int r = 0; r < 4; ++r) {
      const float p0 = q0a[r] + q0b[r];
      const float p1 = q1a[r] + q1b[r];
      const float cur = fmaf(p1, INVMID, p0) + bv1;
      const float reset = (mem1[r] > 1.0f) ? 1.0f : 0.0f;
      mem1[r] = __fsub_rn(__fadd_rn(__fmul_rn(0.9f, mem1[r]), cur), reset);
      ob1[to + (size_t)r * DD] = (mem1[r] > 1.0f) ? 1.0f : 0.0f;
    }
    if (st2) {
#pragma unroll
      for (int r = 0; r < 4; ++r) {
        const float p0 = u0a[r] + u0b[r];
        const float p1 = u1a[r] + u1b[r];
        const float cur = fmaf(p1, INVMID, p0) + bv2;
        const float reset = (mem2[r] > 1.0f) ? 1.0f : 0.0f;
        mem2[r] = __fsub_rn(__fadd_rn(__fmul_rn(0.9f, mem2[r]), cur), reset);
        ob2[to + (size_t)r * DD] = (mem2[r] > 1.0f) ? 1.0f : 0.0f;
      }
    }
  }
}

extern "C" void kernel_launch(void* const* d_in, const int* in_sizes, int n_in,
                              void* d_out, int out_size, void* d_ws, size_t ws_size,
                              hipStream_t stream) {
  const float* x  = (const float*)d_in[0];
  const float* W1 = (const float*)d_in[1];
  const float* b1 = (const float*)d_in[2];
  const float* W2 = (const float*)d_in[3];
  const float* b2 = (const float*)d_in[4];
  float* out = (float*)d_out;

  const size_t w1s_elems = (size_t)2 * HH * K1PAD;    // 409600
  const size_t w2s_elems = (size_t)2 * N2PAD * HH;    // 409600
  unsigned short* W1s = (unsigned short*)d_ws;
  unsigned short* W2s = W1s + w1s_elems;
  float* cur1 = (float*)(W2s + w2s_elems);
  unsigned short* spk1 = (unsigned short*)(cur1 + (size_t)MM * HH);

  dim3 blk(256);

  split_w<<<dim3((HH * K1PAD + 255) / 256), blk, 0, stream>>>(W1, W1s, HH, DD, HH, K1PAD);
  split_w<<<dim3((N2PAD * HH + 255) / 256), blk, 0, stream>>>(W2, W2s, DD, HH, N2PAD, HH);

  // layer 1: cur1[M,256] = X @ W1^T + b1 (BN=256 full-N, 200 blocks x 8 waves)
  gemm1<<<dim3(MM / 128), dim3(512), 0, stream>>>(x, W1s, b1, cur1);

  // layer 1 LIF -> f16 spikes
  lif_scan_h4<<<dim3((BB * HH / 4) / 256), blk, 0, stream>>>(
      (const float4*)cur1, (uint2*)spk1, BB * HH / 4, TT);

  // layer 2 GEMM + LIF fused: 400 single-wave blocks, 2 d-tiles/wave, 0 barriers
  fused_l2<<<dim3(16 * 25), dim3(64), 0, stream>>>(spk1, W2s, b2, out);
}

// Round 14
// 106.351 us; speedup vs baseline: 1.4973x; 1.4973x over previous
//
#include <hip/hip_runtime.h>

typedef __attribute__((ext_vector_type(8))) _Float16 f16x8;
typedef __attribute__((ext_vector_type(4))) float f32x4;

static constexpr int TT = 100, BB = 256, DD = 784, HH = 256;
static constexpr int MM = TT * BB;      // 25600
static constexpr int K1PAD = 800;       // 784 -> 25*32
static constexpr int N2PAD = 800;       // 784 -> 25*32 (W2 row pad)
static constexpr float MIDSC = 2048.0f, INVMID = 1.0f / 2048.0f;

__device__ __forceinline__ unsigned short f2h(float x) {
  _Float16 h = (_Float16)x;
  return *(unsigned short*)&h;
}
__device__ __forceinline__ float h2f(unsigned short u) {
  _Float16 h = *(_Float16*)&u;
  return (float)h;
}
__device__ __forceinline__ void glds16(const void* g, void* l) {
  __builtin_amdgcn_global_load_lds(
      (const __attribute__((address_space(1))) unsigned int*)g,
      (__attribute__((address_space(3))) unsigned int*)l, 16, 0, 0);
}

// Split fp32 W[N][K] into 2 f16 planes [Npad][Kpad]:
//   p0 = f16(w), p1 = f16((w - p0) * 2048); reconstruct p0 + p1/2048 (~2^-22 rel).
__global__ __launch_bounds__(256)
void split_w(const float* __restrict__ W, unsigned short* __restrict__ Ws,
             int N, int K, int Npad, int Kpad) {
  int idx = blockIdx.x * 256 + threadIdx.x;
  int total = Npad * Kpad;
  if (idx >= total) return;
  int row = idx / Kpad, col = idx - row * Kpad;
  float w = (row < N && col < K) ? W[row * K + col] : 0.0f;
  unsigned short h0 = f2h(w);
  float r = (w - h2f(h0)) * MIDSC;
  Ws[idx] = h0;
  Ws[total + idx] = f2h(r);
}

// Layer-1 GEMM (r12 config, verbatim): cur1[M,256] = X @ (2-plane f16 W1)^T + b1.
// BM=BN=128, BK=32, 4 waves 2x2, mfma_f32_16x16x32_f16, dual plane accumulators.
// B: glds triple-buffer, counted vmcnt(4). A: reg-staged binary->f16, ds_written
// one step ahead; packA at step-top.
__global__ __launch_bounds__(256, 2)
void gemm1(const float* __restrict__ X, const unsigned short* __restrict__ Bs,
           const float* __restrict__ bias, float* __restrict__ C) {
  constexpr int Kpad = K1PAD, nkb = Kpad / 32;   // 25
  __shared__ unsigned short Asm[2][128 * 32];      // 16 KB
  __shared__ unsigned short Bsm[3][2][128 * 32];   // 48 KB
  const int tid = threadIdx.x;
  const int bm = blockIdx.x * 128, bn = blockIdx.y * 128;
  const int wid = tid >> 6, lane = tid & 63;
  const int wr = (wid >> 1) * 64, wc = (wid & 1) * 64;
  const int l15 = lane & 15, l4 = lane >> 4;

  f32x4 acc[2][4][4];
#pragma unroll
  for (int s = 0; s < 2; ++s)
#pragma unroll
    for (int m = 0; m < 4; ++m)
#pragma unroll
      for (int n = 0; n < 4; ++n) acc[s][m][n] = (f32x4){0.f, 0.f, 0.f, 0.f};

  const int rl = wid * 32 + (lane >> 2);
  const int ce = ((lane & 3) ^ ((lane >> 3) & 3)) * 8;
  const size_t pstr = (size_t)HH * Kpad;
  const unsigned short* bsrc0 = Bs + (size_t)(bn + rl) * Kpad + ce;
  const unsigned short* bsrc1 = Bs + (size_t)(bn + rl + 16) * Kpad + ce;

  const int rdsw = (l4 ^ ((l15 >> 1) & 3)) * 8;

  const int r0 = tid >> 2;
  const int c0log = (tid & 3) * 8;
  const int c0phys = ((tid & 3) ^ ((tid >> 3) & 3)) * 8;

  float4 aA[4], aB[4];

  auto loadA = [&](int kb, float4 (&d)[4]) {
    const int col = kb * 32 + c0log;
    const bool ok = col < DD;
    const int colc = ok ? col : 0;
    const float* p0 = &X[(size_t)(bm + r0) * DD + colc];
    const float* p1 = &X[(size_t)(bm + r0 + 64) * DD + colc];
    d[0] = *(const float4*)p0; d[1] = *(const float4*)(p0 + 4);
    d[2] = *(const float4*)p1; d[3] = *(const float4*)(p1 + 4);
    if (!ok) {
      const float4 z = make_float4(0.f, 0.f, 0.f, 0.f);
      d[0] = z; d[1] = z; d[2] = z; d[3] = z;
    }
  };
  auto packA = [&](int bi, const float4 (&s_)[4]) {
    const unsigned ONE = 0x3C00u;
    auto pk = [&](float a, float b) {
      return (a != 0.f ? ONE : 0u) | (b != 0.f ? (ONE << 16) : 0u);
    };
    uint4 v0, v1;
    v0.x = pk(s_[0].x, s_[0].y); v0.y = pk(s_[0].z, s_[0].w);
    v0.z = pk(s_[1].x, s_[1].y); v0.w = pk(s_[1].z, s_[1].w);
    v1.x = pk(s_[2].x, s_[2].y); v1.y = pk(s_[2].z, s_[2].w);
    v1.z = pk(s_[3].x, s_[3].y); v1.w = pk(s_[3].z, s_[3].w);
    *(uint4*)&Asm[bi][r0 * 32 + c0phys] = v0;
    *(uint4*)&Asm[bi][(r0 + 64) * 32 + c0phys] = v1;
  };
  auto stageB = [&](int t) {
    const int k0 = t * 32, bi = t % 3;
    glds16(bsrc0 + k0, &Bsm[bi][0][(wid * 32) * 32]);
    glds16(bsrc1 + k0, &Bsm[bi][0][(wid * 32 + 16) * 32]);
    glds16(bsrc0 + pstr + k0, &Bsm[bi][1][(wid * 32) * 32]);
    glds16(bsrc1 + pstr + k0, &Bsm[bi][1][(wid * 32 + 16) * 32]);
  };
  auto compute = [&](int kb) {
    const int cb = kb & 1, b3 = kb % 3;
    f16x8 afr[4];
#pragma unroll
    for (int m = 0; m < 4; ++m)
      afr[m] = *(const f16x8*)&Asm[cb][(wr + m * 16 + l15) * 32 + rdsw];
#pragma unroll
    for (int s = 0; s < 2; ++s) {
      f16x8 bfr[4];
#pragma unroll
      for (int n = 0; n < 4; ++n)
        bfr[n] = *(const f16x8*)&Bsm[b3][s][(wc + n * 16 + l15) * 32 + rdsw];
#pragma unroll
      for (int m = 0; m < 4; ++m)
#pragma unroll
        for (int n = 0; n < 4; ++n)
          acc[s][m][n] = __builtin_amdgcn_mfma_f32_16x16x32_f16(afr[m], bfr[n], acc[s][m][n], 0, 0, 0);
    }
  };
  auto stepK = [&](int kb, const float4 (&pk_)[4], float4 (&ld_)[4]) {
    if (kb + 1 < nkb) packA((kb + 1) & 1, pk_);
    if (kb + 2 < nkb) stageB(kb + 2);
    compute(kb);
    __builtin_amdgcn_sched_barrier(0);
    if (kb + 2 < nkb) asm volatile("s_waitcnt vmcnt(4)" ::: "memory");
    else              asm volatile("s_waitcnt vmcnt(0)" ::: "memory");
    if (kb + 2 < nkb) loadA(kb + 2, ld_);
    asm volatile("s_waitcnt lgkmcnt(0)" ::: "memory");
    __builtin_amdgcn_sched_barrier(0);
    __builtin_amdgcn_s_barrier();
    __builtin_amdgcn_sched_barrier(0);
  };

  loadA(0, aA);
  stageB(0); stageB(1);
  asm volatile("s_waitcnt vmcnt(8)" ::: "memory");
  packA(0, aA);
  loadA(1, aB);
  asm volatile("s_waitcnt vmcnt(8)" ::: "memory");
  asm volatile("s_waitcnt lgkmcnt(0)" ::: "memory");
  __builtin_amdgcn_s_barrier();
  __builtin_amdgcn_sched_barrier(0);

  for (int kb2 = 0; kb2 < nkb; kb2 += 2) {
    stepK(kb2, aB, aA);
    if (kb2 + 1 < nkb) stepK(kb2 + 1, aA, aB);
  }

#pragma unroll
  for (int m = 0; m < 4; ++m)
#pragma unroll
    for (int n = 0; n < 4; ++n) {
      const int col = bn + wc + n * 16 + l15;
      const float bv = bias[col];
#pragma unroll
      for (int r = 0; r < 4; ++r) {
        const int row = bm + wr + m * 16 + l4 * 4 + r;
        C[(size_t)row * HH + col] = fmaf(acc[1][m][n][r], INVMID, acc[0][m][n][r]) + bv;
      }
    }
}

// fp32 currents -> f16 spikes, 4 elems/thread
__global__ __launch_bounds__(256)
void lif_scan_h4(const float4* __restrict__ cur, uint2* __restrict__ spk,
                 int NE4, int nt) {
  const int tid = blockIdx.x * 256 + threadIdx.x;
  float4 mem = make_float4(0.f, 0.f, 0.f, 0.f);
  auto step1 = [](float& m, float c) {
    const float reset = (m > 1.0f) ? 1.0f : 0.0f;
    m = __fsub_rn(__fadd_rn(__fmul_rn(0.9f, m), c), reset);
    return (m > 1.0f);
  };
#pragma unroll 4
  for (int t = 0; t < nt; ++t) {
    const float4 c = cur[(size_t)t * NE4 + tid];
    unsigned s0 = step1(mem.x, c.x) ? 0x3C00u : 0u;
    unsigned s1 = step1(mem.y, c.y) ? 0x3C00u : 0u;
    unsigned s2 = step1(mem.z, c.z) ? 0x3C00u : 0u;
    unsigned s3 = step1(mem.w, c.w) ? 0x3C00u : 0u;
    uint2 o;
    o.x = s0 | (s1 << 16);
    o.y = s2 | (s3 << 16);
    spk[(size_t)t * NE4 + tid] = o;
  }
}

// Fused layer-2 GEMM + LIF v8: r12's single-wave zero-barrier skeleton,
// software-pipelined at 2-t granularity. Per pair (p, p+1): issue stage(p+2),
// stage(p+3); ONE counted vmcnt; read rA -> MFMA(p); issue rB ds_reads BEFORE
// LIF(p) so their latency hides under the epilogue; MFMA(p+1); LIF(p+1).
// FIFO at pair-p wait (drain stage(p+1)): newer = stores(p-2):4 + stores(p-1):4
// + stage(p+2):8 + stage(p+3):8 = 24 -> vmcnt(24); p=0 -> 16; p=98 -> 8.
// MFMA chains + LIF ops bitwise identical to r12.
__global__ __launch_bounds__(64)
void fused_l2(const unsigned short* __restrict__ spk1,   // [100][256][256] f16
              const unsigned short* __restrict__ W2s,    // 2 planes [800][256] f16
              const float* __restrict__ b2, float* __restrict__ out) {
  __shared__ unsigned short Asm[4][16 * 256];   // 32 KB ring
  const int lane = threadIdx.x;                  // 64
  const int l15 = lane & 15, l4 = lane >> 4;
  const int bb = blockIdx.x / 49, dd = blockIdx.x - bb * 49;  // 16 x 49
  const int b0 = bb * 16, d0 = dd * 16;

  const unsigned short* asrc[8];
#pragma unroll
  for (int i = 0; i < 8; ++i) {
    const int r = 2 * i + (lane >> 5);
    const int e = ((lane & 31) * 8) ^ ((r & 7) << 3);
    asrc[i] = spk1 + (size_t)(b0 + r) * HH + e;
  }
  auto stageA = [&](int t) {
    const size_t toff = (size_t)t * (BB * HH);
    unsigned short* dst = &Asm[t & 3][0];
#pragma unroll
    for (int i = 0; i < 8; ++i)
      glds16(asrc[i] + toff, dst + 2 * i * 256);
  };

  stageA(0);
  stageA(1);

  f16x8 wfr[2][8];
  const unsigned short* wb = W2s + (size_t)(d0 + l15) * HH + l4 * 8;
#pragma unroll
  for (int s = 0; s < 2; ++s)
#pragma unroll
    for (int ks = 0; ks < 8; ++ks)
      wfr[s][ks] = *(const f16x8*)(wb + (size_t)s * (N2PAD * HH) + ks * 32);
  const float bv = b2[d0 + l15];

  asm volatile("s_waitcnt vmcnt(0)" ::: "memory");
  __builtin_amdgcn_sched_barrier(0);

  f32x4 mem = (f32x4){0.f, 0.f, 0.f, 0.f};
  float* obase = out + (size_t)(b0 + l4 * 4) * DD + d0 + l15;

  // swizzled LDS fragment offsets (ushort index within a buffer)
  int roff[8];
#pragma unroll
  for (int ks = 0; ks < 8; ++ks)
    roff[ks] = l15 * 256 + ((ks * 32 + l4 * 8) ^ ((l15 & 7) << 3));

  for (int p = 0; p < TT; p += 2) {
    if (p + 2 < TT) { stageA(p + 2); stageA(p + 3); }
    if (p == 0)            asm volatile("s_waitcnt vmcnt(16)" ::: "memory");
    else if (p + 2 < TT)   asm volatile("s_waitcnt vmcnt(24)" ::: "memory");
    else                   asm volatile("s_waitcnt vmcnt(8)"  ::: "memory");
    __builtin_amdgcn_sched_barrier(0);

    const unsigned short* bufA = &Asm[p & 3][0];
    const unsigned short* bufB = &Asm[(p + 1) & 3][0];

    // t = p: read fragments, MFMA (4 chains of 4, identical order to r12)
    f16x8 rA[8];
#pragma unroll
    for (int ks = 0; ks < 8; ++ks)
      rA[ks] = *(const f16x8*)&bufA[roff[ks]];
    f32x4 p0a = (f32x4){0.f, 0.f, 0.f, 0.f}, p0b = p0a, p1a = p0a, p1b = p0a;
#pragma unroll
    for (int ks = 0; ks < 4; ++ks) {
      p0a = __builtin_amdgcn_mfma_f32_16x16x32_f16(rA[ks], wfr[0][ks], p0a, 0, 0, 0);
      p1a = __builtin_amdgcn_mfma_f32_16x16x32_f16(rA[ks], wfr[1][ks], p1a, 0, 0, 0);
    }
#pragma unroll
    for (int ks = 4; ks < 8; ++ks) {
      p0b = __builtin_amdgcn_mfma_f32_16x16x32_f16(rA[ks], wfr[0][ks], p0b, 0, 0, 0);
      p1b = __builtin_amdgcn_mfma_f32_16x16x32_f16(rA[ks], wfr[1][ks], p1b, 0, 0, 0);
    }

    // issue t = p+1 fragment reads early: latency hides under LIF(p) + stores(p)
    f16x8 rB[8];
#pragma unroll
    for (int ks = 0; ks < 8; ++ks)
      rB[ks] = *(const f16x8*)&bufB[roff[ks]];

    // LIF + stores for t = p
    {
      float* op = obase + (size_t)p * ((size_t)BB * DD);
#pragma unroll
      for (int r = 0; r < 4; ++r) {
        const float p0 = p0a[r] + p0b[r];
        const float p1 = p1a[r] + p1b[r];
        const float cur = fmaf(p1, INVMID, p0) + bv;
        const float reset = (mem[r] > 1.0f) ? 1.0f : 0.0f;
        mem[r] = __fsub_rn(__fadd_rn(__fmul_rn(0.9f, mem[r]), cur), reset);
        op[(size_t)r * DD] = (mem[r] > 1.0f) ? 1.0f : 0.0f;
      }
    }

    // t = p+1: MFMA + LIF + stores
    f32x4 q0a = (f32x4){0.f, 0.f, 0.f, 0.f}, q0b = q0a, q1a = q0a, q1b = q0a;
#pragma unroll
    for (int ks = 0; ks < 4; ++ks) {
      q0a = __builtin_amdgcn_mfma_f32_16x16x32_f16(rB[ks], wfr[0][ks], q0a, 0, 0, 0);
      q1a = __builtin_amdgcn_mfma_f32_16x16x32_f16(rB[ks], wfr[1][ks], q1a, 0, 0, 0);
    }
#pragma unroll
    for (int ks = 4; ks < 8; ++ks) {
      q0b = __builtin_amdgcn_mfma_f32_16x16x32_f16(rB[ks], wfr[0][ks], q0b, 0, 0, 0);
      q1b = __builtin_amdgcn_mfma_f32_16x16x32_f16(rB[ks], wfr[1][ks], q1b, 0, 0, 0);
    }
    {
      float* op = obase + (size_t)(p + 1) * ((size_t)BB * DD);
#pragma unroll
      for (int r = 0; r < 4; ++r) {
        const float p0 = q0a[r] + q0b[r];
        const float p1 = q1a[r] + q1b[r];
        const float cur = fmaf(p1, INVMID, p0) + bv;
        const float reset = (mem[r] > 1.0f) ? 1.0f : 0.0f;
        mem[r] = __fsub_rn(__fadd_rn(__fmul_rn(0.9f, mem[r]), cur), reset);
        op[(size_t)r * DD] = (mem[r] > 1.0f) ? 1.0f : 0.0f;
      }
    }
  }
}

extern "C" void kernel_launch(void* const* d_in, const int* in_sizes, int n_in,
                              void* d_out, int out_size, void* d_ws, size_t ws_size,
                              hipStream_t stream) {
  const float* x  = (const float*)d_in[0];
  const float* W1 = (const float*)d_in[1];
  const float* b1 = (const float*)d_in[2];
  const float* W2 = (const float*)d_in[3];
  const float* b2 = (const float*)d_in[4];
  float* out = (float*)d_out;

  const size_t w1s_elems = (size_t)2 * HH * K1PAD;    // 409600
  const size_t w2s_elems = (size_t)2 * N2PAD * HH;    // 409600
  unsigned short* W1s = (unsigned short*)d_ws;
  unsigned short* W2s = W1s + w1s_elems;
  float* cur1 = (float*)(W2s + w2s_elems);
  unsigned short* spk1 = (unsigned short*)(cur1 + (size_t)MM * HH);

  dim3 blk(256);

  split_w<<<dim3((HH * K1PAD + 255) / 256), blk, 0, stream>>>(W1, W1s, HH, DD, HH, K1PAD);
  split_w<<<dim3((N2PAD * HH + 255) / 256), blk, 0, stream>>>(W2, W2s, DD, HH, N2PAD, HH);

  // layer 1: cur1[M,256] = X @ W1^T + b1 (r12 config: 400 blocks x 4 waves)
  gemm1<<<dim3(MM / 128, HH / 128), blk, 0, stream>>>(x, W1s, b1, cur1);

  // layer 1 LIF -> f16 spikes
  lif_scan_h4<<<dim3((BB * HH / 4) / 256), blk, 0, stream>>>(
      (const float4*)cur1, (uint2*)spk1, BB * HH / 4, TT);

  // layer 2 GEMM + LIF fused: 784 single-wave blocks, zero barriers, 2t pipeline
  fused_l2<<<dim3(16 * 49), dim3(64), 0, stream>>>(spk1, W2s, b2, out);
}